// Round 6
// baseline (1600.846 us; speedup 1.0000x reference)
//
#include <hip/hip_runtime.h>

#define N_NODES 100000
#define N_EDGES 1600000
#define D 32
#define ED 8
#define NEG_SLOPE 0.01f
#define BSH 7                                   // 128 nodes per bucket
#define BNODES 128
#define NB ((N_NODES + BNODES - 1) / BNODES)    // 782 buckets

typedef unsigned int uint;
typedef unsigned short ushort;

__device__ __forceinline__ uint bf16_rne(float f) {
    uint u = __float_as_uint(f);
    return (u + 0x7fffu + ((u >> 16) & 1u)) >> 16;
}
__device__ __forceinline__ uint pack2(float lo, float hi) {
    return bf16_rne(lo) | (bf16_rne(hi) << 16);
}
__device__ __forceinline__ float bf_lo(uint u) { return __uint_as_float(u << 16); }
__device__ __forceinline__ float bf_hi(uint u) { return __uint_as_float(u & 0xffff0000u); }
__device__ __forceinline__ float bf_us(ushort u) { return __uint_as_float(((uint)u) << 16); }

// ---------------- x -> bf16 pack ----------------
__global__ __launch_bounds__(256) void pack_x_kernel(
    const float* __restrict__ x, ushort* __restrict__ xb)
{
    int i = blockIdx.x * 256 + threadIdx.x;     // over N*D/4
    if (i >= N_NODES * D / 4) return;
    float4 f = ((const float4*)x)[i];
    ((uint2*)xb)[i] = make_uint2(pack2(f.x, f.y), pack2(f.z, f.w));
}

// ---------------- bucket binning ----------------
__global__ __launch_bounds__(256) void bucket_hist_kernel(
    const int* __restrict__ dst, int* __restrict__ bcnt)
{
    __shared__ int h[NB];
    for (int i = threadIdx.x; i < NB; i += 256) h[i] = 0;
    __syncthreads();
    for (int e = blockIdx.x * 256 + threadIdx.x; e < N_EDGES; e += gridDim.x * 256)
        atomicAdd(&h[dst[e] >> BSH], 1);
    __syncthreads();
    for (int i = threadIdx.x; i < NB; i += 256)
        if (h[i]) atomicAdd(&bcnt[i], h[i]);
}

// exclusive scan of padded bucket counts (pad each bucket start to 4-edge align)
__global__ __launch_bounds__(1024) void bucket_scan_kernel(
    const int* __restrict__ bcnt, int* __restrict__ boff,
    int* __restrict__ bend, int* __restrict__ cur)
{
    __shared__ int s[1024];
    int t = threadIdx.x;
    int c  = (t < NB) ? bcnt[t] : 0;
    int cp = (c + 3) & ~3;
    s[t] = cp;
    __syncthreads();
    for (int off = 1; off < 1024; off <<= 1) {
        int u = (t >= off) ? s[t - off] : 0;
        __syncthreads();
        s[t] += u;
        __syncthreads();
    }
    if (t < NB) {
        int start = s[t] - cp;
        boff[t] = start;
        bend[t] = start + c;
        cur[t]  = start;
    }
}

// append edges into bucket-contiguous regions: meta {src|dl<<20} + ea bf16x8
__global__ __launch_bounds__(256) void bin_pass_kernel(
    const int*   __restrict__ src,
    const int*   __restrict__ dst,
    const float* __restrict__ edge_attr,
    int*         __restrict__ cur,
    uint*        __restrict__ meta,
    uint4*       __restrict__ ea2)
{
    int e = blockIdx.x * 256 + threadIdx.x;
    if (e >= N_EDGES) return;
    int dn = dst[e];
    int bkt = dn >> BSH, dl = dn & (BNODES - 1);
    int pos = atomicAdd(&cur[bkt], 1);
    meta[pos] = (uint)src[e] | ((uint)dl << 20);
    const float4* e4 = (const float4*)edge_attr;
    float4 a = e4[(long)e * 2], c = e4[(long)e * 2 + 1];
    ea2[pos] = make_uint4(pack2(a.x, a.y), pack2(a.z, a.w),
                          pack2(c.x, c.y), pack2(c.z, c.w));
}

// ---------------- bucket GINE layer: edge-parallel + LDS agg ----------------
__global__ __launch_bounds__(256) void gine_bucket_kernel(
    const ushort* __restrict__ xb_in,
    ushort*       __restrict__ xb_out,
    float*        __restrict__ f32_out,   // last layer only
    const int*    __restrict__ boff,
    const int*    __restrict__ bend,
    const uint*   __restrict__ meta,
    const uint4*  __restrict__ ea2,
    const float*  __restrict__ W,    // [32][32]
    const float*  __restrict__ b,    // [32]
    const float*  __restrict__ We,   // [8][32]
    const float*  __restrict__ be)   // [32]
{
    __shared__ float agg[BNODES * D];   // 16 KB, lane d -> bank d (conflict-free)
    __shared__ float W_s[D * D];        // 4 KB
    const int t = threadIdx.x;
    const int g = t >> 5, d = t & 31;
    for (int i = t; i < BNODES * D; i += 256) agg[i] = 0.0f;
    for (int i = t; i < D * D; i += 256) W_s[i] = W[i];

    float wer[ED];
#pragma unroll
    for (int k = 0; k < ED; ++k) wer[k] = We[k * D + d];
    const float bed = be[d];
    const float bd  = b[d];
    __syncthreads();

    const int bId = blockIdx.x;
    const int e0 = boff[bId], e1 = bend[bId];

    // edge phase: 8 groups x 4 edges per iteration, edge-parallel
    for (int base = e0 + g * 4; base < e1; base += 32) {
        uint4 m4 = *(const uint4*)(meta + base);  // broadcast 16B (base % 4 == 0)
        uint mm0 = m4.x, mm1 = m4.y, mm2 = m4.z, mm3 = m4.w;

        bool ok[4]; int sj[4], dl[4]; float xv[4]; uint4 eav[4];
#pragma unroll
        for (int j = 0; j < 4; ++j) {
            uint m = (j == 0) ? mm0 : (j == 1) ? mm1 : (j == 2) ? mm2 : mm3;
            ok[j] = (base + j) < e1;
            m = ok[j] ? m : 0u;
            sj[j] = (int)(m & 0xFFFFFu);
            dl[j] = (int)((m >> 20) & (BNODES - 1));
            xv[j]  = bf_us(xb_in[sj[j] * D + d]);   // 64B coalesced gather
            eav[j] = ea2[base + j];                  // broadcast 16B (slack-padded)
        }
#pragma unroll
        for (int j = 0; j < 4; ++j) {
            float e = bed;
            e += bf_lo(eav[j].x) * wer[0];
            e += bf_hi(eav[j].x) * wer[1];
            e += bf_lo(eav[j].y) * wer[2];
            e += bf_hi(eav[j].y) * wer[3];
            e += bf_lo(eav[j].z) * wer[4];
            e += bf_hi(eav[j].z) * wer[5];
            e += bf_lo(eav[j].w) * wer[6];
            e += bf_hi(eav[j].w) * wer[7];
            float msg = fmaxf(xv[j] + e, 0.0f);
            if (ok[j]) atomicAdd(&agg[dl[j] * D + d], msg);
        }
    }
    __syncthreads();

    // node phase: group g handles local nodes [g*16, g*16+16)
    for (int ln = g * 16; ln < g * 16 + 16; ++ln) {
        int n = bId * BNODES + ln;
        if (n >= N_NODES) break;
        float h = bf_us(xb_in[n * D + d]) + agg[ln * D + d];
        float o = bd;
#pragma unroll
        for (int k = 0; k < D; ++k)
            o += __shfl(h, k, 32) * W_s[k * D + d];
        o = o > 0.0f ? o : NEG_SLOPE * o;
        xb_out[n * D + d] = (ushort)bf16_rne(o);
        if (f32_out) f32_out[n * D + d] = o;
    }
}

// ---------------- fallback (round-1 atomic path) ----------------
__global__ __launch_bounds__(256) void gine_edge_kernel(
    const float* __restrict__ x, const float* __restrict__ edge_attr,
    const float* __restrict__ We, const float* __restrict__ be,
    const int* __restrict__ src, const int* __restrict__ dst,
    float* __restrict__ agg)
{
    __shared__ float We_s[ED * D];
    __shared__ float be_s[D];
    int t = threadIdx.x;
    if (t < ED * D) We_s[t] = We[t];
    if (t < D) be_s[t] = be[t];
    __syncthreads();
    long gtid = (long)blockIdx.x * blockDim.x + t;
    int e = (int)(gtid >> 5), d = (int)(gtid & 31);
    if (e >= N_EDGES) return;
    int s = src[e], dn = dst[e];
    float acc = be_s[d];
#pragma unroll
    for (int k = 0; k < ED; ++k)
        acc += edge_attr[(long)e * ED + k] * We_s[k * D + d];
    float m = fmaxf(x[(long)s * D + d] + acc, 0.0f);
    atomicAdd(&agg[(long)dn * D + d], m);
}

__global__ __launch_bounds__(256) void gine_node_kernel(
    float* __restrict__ x, const float* __restrict__ agg,
    const float* __restrict__ W, const float* __restrict__ b)
{
    __shared__ float W_s[D * D];
    __shared__ float b_s[D];
    int t = threadIdx.x;
    for (int i = t; i < D * D; i += 256) W_s[i] = W[i];
    if (t < D) b_s[t] = b[t];
    __syncthreads();
    long gtid = (long)blockIdx.x * blockDim.x + t;
    int n = (int)(gtid >> 5), d = (int)(gtid & 31);
    if (n >= N_NODES) return;
    float h = x[(long)n * D + d] + agg[(long)n * D + d];
    float acc = b_s[d];
#pragma unroll
    for (int k = 0; k < D; ++k)
        acc += __shfl(h, k, D) * W_s[k * D + d];
    x[(long)n * D + d] = acc > 0.0f ? acc : NEG_SLOPE * acc;
}

// ---------------- launch ----------------

extern "C" void kernel_launch(void* const* d_in, const int* in_sizes, int n_in,
                              void* d_out, int out_size, void* d_ws, size_t ws_size,
                              hipStream_t stream) {
    const float* x_in      = (const float*)d_in[0];
    const float* edge_attr = (const float*)d_in[1];
    const float* W         = (const float*)d_in[2];
    const float* b         = (const float*)d_in[3];
    const float* We        = (const float*)d_in[4];
    const float* be        = (const float*)d_in[5];
    const int*   ei        = (const int*)d_in[6];
    const int* src = ei;
    const int* dst = ei + N_EDGES;

    const size_t xbytes  = (size_t)N_NODES * D * sizeof(float);
    const size_t xbbytes = (size_t)N_NODES * D * sizeof(ushort);     // 6.4 MB
    const size_t epad    = (size_t)N_EDGES + 4 * NB + 16;            // slack for pad

    auto align = [](size_t v) { return (v + 255) & ~(size_t)255; };
    size_t off_xba  = 0;
    size_t off_xbb  = align(off_xba + xbbytes);
    size_t off_bcnt = align(off_xbb + xbbytes);                  // NB ints
    size_t off_boff = align(off_bcnt + NB * sizeof(int));        // NB
    size_t off_bend = align(off_boff + NB * sizeof(int));        // NB
    size_t off_cur  = align(off_bend + NB * sizeof(int));        // NB
    size_t off_meta = align(off_cur + NB * sizeof(int));         // epad uints
    size_t off_ea2  = align(off_meta + epad * sizeof(uint));     // epad uint4
    size_t need     = off_ea2 + epad * sizeof(uint4);

    if (ws_size >= need) {
        char* ws = (char*)d_ws;
        ushort* xbA  = (ushort*)(ws + off_xba);
        ushort* xbB  = (ushort*)(ws + off_xbb);
        int*  bcnt   = (int*)   (ws + off_bcnt);
        int*  boff   = (int*)   (ws + off_boff);
        int*  bendp  = (int*)   (ws + off_bend);
        int*  cur    = (int*)   (ws + off_cur);
        uint* meta   = (uint*)  (ws + off_meta);
        uint4* ea2   = (uint4*) (ws + off_ea2);

        pack_x_kernel<<<(N_NODES * D / 4 + 255) / 256, 256, 0, stream>>>(x_in, xbA);
        hipMemsetAsync(bcnt, 0, NB * sizeof(int), stream);
        bucket_hist_kernel<<<256, 256, 0, stream>>>(dst, bcnt);
        bucket_scan_kernel<<<1, 1024, 0, stream>>>(bcnt, boff, bendp, cur);
        bin_pass_kernel<<<(N_EDGES + 255) / 256, 256, 0, stream>>>(
            src, dst, edge_attr, cur, meta, ea2);

        float* xout = (float*)d_out;
        dim3 blk(256), grid(NB);
        gine_bucket_kernel<<<grid, blk, 0, stream>>>(xbA, xbB, nullptr, boff, bendp,
            meta, ea2, W, b, We, be);
        gine_bucket_kernel<<<grid, blk, 0, stream>>>(xbB, xbA, nullptr, boff, bendp,
            meta, ea2, W + D * D, b + D, We + ED * D, be + D);
        gine_bucket_kernel<<<grid, blk, 0, stream>>>(xbA, xbB, xout, boff, bendp,
            meta, ea2, W + 2 * D * D, b + 2 * D, We + 2 * ED * D, be + 2 * D);
    } else {
        float* x = (float*)d_out;
        float* agg = (float*)d_ws;
        hipMemcpyAsync(x, x_in, xbytes, hipMemcpyDeviceToDevice, stream);
        dim3 eblk(256), egrid(((long)N_EDGES * D + 255) / 256);
        dim3 nblk(256), ngrid(((long)N_NODES * D + 255) / 256);
        for (int l = 0; l < 3; ++l) {
            hipMemsetAsync(agg, 0, xbytes, stream);
            gine_edge_kernel<<<egrid, eblk, 0, stream>>>(
                x, edge_attr, We + (size_t)l * ED * D, be + (size_t)l * D, src, dst, agg);
            gine_node_kernel<<<ngrid, nblk, 0, stream>>>(
                x, agg, W + (size_t)l * D * D, b + (size_t)l * D);
        }
    }
}

// Round 7
// 580.077 us; speedup vs baseline: 2.7597x; 2.7597x over previous
//
#include <hip/hip_runtime.h>

#define N_NODES 100000
#define N_EDGES 1600000
#define D 32
#define ED 8
#define NEG_SLOPE 0.01f
#define NBLK ((N_NODES + 1023) / 1024)  // 98 scan blocks

typedef unsigned int uint;
typedef unsigned short ushort;

__device__ __forceinline__ uint bf16_rne(float f) {
    uint u = __float_as_uint(f);
    return (u + 0x7fffu + ((u >> 16) & 1u)) >> 16;
}
__device__ __forceinline__ uint pack2(float lo, float hi) {
    return bf16_rne(lo) | (bf16_rne(hi) << 16);
}
__device__ __forceinline__ float bf_lo(uint u) { return __uint_as_float(u << 16); }
__device__ __forceinline__ float bf_hi(uint u) { return __uint_as_float(u & 0xffff0000u); }
__device__ __forceinline__ float bf_us(ushort u) { return __uint_as_float(((uint)u) << 16); }

// ---------------- x -> bf16 pack ----------------
__global__ __launch_bounds__(256) void pack_x_kernel(
    const float* __restrict__ x, ushort* __restrict__ xb)
{
    int i = blockIdx.x * 256 + threadIdx.x;     // over N*D/4
    if (i >= N_NODES * D / 4) return;
    float4 f = ((const float4*)x)[i];
    ((uint2*)xb)[i] = make_uint2(pack2(f.x, f.y), pack2(f.z, f.w));
}

// ---------------- CSR build ----------------
__global__ __launch_bounds__(256) void hist_kernel(
    const int* __restrict__ dst, int* __restrict__ deg)
{
    int i = blockIdx.x * 256 + threadIdx.x;     // over E/4
    if (i >= N_EDGES / 4) return;
    int4 dd = ((const int4*)dst)[i];
    atomicAdd(&deg[dd.x], 1);
    atomicAdd(&deg[dd.y], 1);
    atomicAdd(&deg[dd.z], 1);
    atomicAdd(&deg[dd.w], 1);
}

__global__ __launch_bounds__(1024) void scan_phase1(
    const int* __restrict__ deg, int* __restrict__ bsums)
{
    __shared__ int s[1024];
    int t = threadIdx.x;
    int i = blockIdx.x * 1024 + t;
    s[t] = (i < N_NODES) ? deg[i] : 0;
    __syncthreads();
    for (int off = 512; off > 0; off >>= 1) {
        if (t < off) s[t] += s[t + off];
        __syncthreads();
    }
    if (t == 0) bsums[blockIdx.x] = s[0];
}

__global__ __launch_bounds__(128) void scan_phase2(int* __restrict__ bsums)
{
    __shared__ int s[128];
    int t = threadIdx.x;
    int v = (t < NBLK) ? bsums[t] : 0;
    s[t] = v;
    __syncthreads();
    for (int off = 1; off < 128; off <<= 1) {
        int u = (t >= off) ? s[t - off] : 0;
        __syncthreads();
        s[t] += u;
        __syncthreads();
    }
    if (t < NBLK) bsums[t] = s[t] - v;  // exclusive
}

__global__ __launch_bounds__(1024) void scan_phase3(
    const int* __restrict__ deg, const int* __restrict__ bsums,
    int* __restrict__ row_ptr, int* __restrict__ offs)
{
    __shared__ int s[1024];
    int t = threadIdx.x;
    int i = blockIdx.x * 1024 + t;
    int v = (i < N_NODES) ? deg[i] : 0;
    s[t] = v;
    __syncthreads();
    for (int off = 1; off < 1024; off <<= 1) {
        int u = (t >= off) ? s[t - off] : 0;
        __syncthreads();
        s[t] += u;
        __syncthreads();
    }
    int excl = bsums[blockIdx.x] + s[t] - v;
    if (i < N_NODES) { row_ptr[i] = excl; offs[i] = excl; }
    else if (i == N_NODES) row_ptr[i] = excl;
}

// direct scatter: 32B-slot record {ea bf16x8 (16B, aligned), src}, 20B burst -> 1 line
__global__ __launch_bounds__(256) void scatter_rec_kernel(
    const int*   __restrict__ src,
    const int*   __restrict__ dst,
    const float* __restrict__ edge_attr,
    int*         __restrict__ offs,
    uint*        __restrict__ rec)   // 8 uints per record
{
    int e = blockIdx.x * 256 + threadIdx.x;
    if (e >= N_EDGES) return;
    int pos = atomicAdd(&offs[dst[e]], 1);
    const float4* ea4 = (const float4*)edge_attr;
    float4 a = ea4[(long)e * 2];
    float4 c = ea4[(long)e * 2 + 1];
    uint* r = rec + (long)pos * 8;
    *(uint4*)r = make_uint4(pack2(a.x, a.y), pack2(a.z, a.w),
                            pack2(c.x, c.y), pack2(c.z, c.w));  // 16B
    r[4] = (uint)src[e];                                        // +4B same line
}

// ---------------- fused GINE layer (broadcast loads, no shfl in edge loop) ----
__global__ __launch_bounds__(256) void gine_fused3_kernel(
    const ushort* __restrict__ xb_in,
    ushort*       __restrict__ xb_out,
    float*        __restrict__ f32_out,   // last layer only
    const int*    __restrict__ row_ptr,
    const uint*   __restrict__ rec,
    const float*  __restrict__ W,    // [32][32]
    const float*  __restrict__ b,    // [32]
    const float*  __restrict__ We,   // [8][32]
    const float*  __restrict__ be)   // [32]
{
    __shared__ float W_s[D * D];
    const int t = threadIdx.x;
    for (int i = t; i < D * D; i += 256) W_s[i] = W[i];

    const int n = blockIdx.x * 8 + (t >> 5);
    const int d = t & 31;

    float wer[ED];
#pragma unroll
    for (int k = 0; k < ED; ++k) wer[k] = We[k * D + d];
    const float bed = be[d];
    const float bd  = b[d];
    __syncthreads();
    if (n >= N_NODES) return;

    const int row  = row_ptr[n];
    const int rend = row_ptr[n + 1];

    float selfx = bf_us(xb_in[n * D + d]);  // 64B coalesced per group

    float acc = 0.0f;
    int pos = row;
    // full batches of 8: broadcast (uniform-address) loads, no predication
    for (; pos + 8 <= rend; pos += 8) {
        const uint* r = rec + pos * 8;      // 32-bit math
        uint4 ea[8]; int sj[8];
#pragma unroll
        for (int j = 0; j < 8; ++j) {
            ea[j] = *(const uint4*)(r + j * 8);   // broadcast 16B
            sj[j] = (int)r[j * 8 + 4];            // broadcast 4B
        }
        float xv[8];
#pragma unroll
        for (int j = 0; j < 8; ++j)
            xv[j] = bf_us(xb_in[sj[j] * D + d]);  // 8 independent 64B gathers
#pragma unroll
        for (int j = 0; j < 8; ++j) {
            float e = bed;
            e += bf_lo(ea[j].x) * wer[0];
            e += bf_hi(ea[j].x) * wer[1];
            e += bf_lo(ea[j].y) * wer[2];
            e += bf_hi(ea[j].y) * wer[3];
            e += bf_lo(ea[j].z) * wer[4];
            e += bf_hi(ea[j].z) * wer[5];
            e += bf_lo(ea[j].w) * wer[6];
            e += bf_hi(ea[j].w) * wer[7];
            acc += fmaxf(xv[j] + e, 0.0f);
        }
    }
    // tail (< 8 edges)
    for (; pos < rend; ++pos) {
        const uint* r = rec + pos * 8;
        uint4 eaj = *(const uint4*)r;
        int sj = (int)r[4];
        float xvj = bf_us(xb_in[sj * D + d]);
        float e = bed;
        e += bf_lo(eaj.x) * wer[0];
        e += bf_hi(eaj.x) * wer[1];
        e += bf_lo(eaj.y) * wer[2];
        e += bf_hi(eaj.y) * wer[3];
        e += bf_lo(eaj.z) * wer[4];
        e += bf_hi(eaj.z) * wer[5];
        e += bf_lo(eaj.w) * wer[6];
        e += bf_hi(eaj.w) * wer[7];
        acc += fmaxf(xvj + e, 0.0f);
    }

    float h = selfx + acc;
    float o = bd;
#pragma unroll
    for (int k = 0; k < D; ++k)
        o += __shfl(h, k, 32) * W_s[k * D + d];
    o = o > 0.0f ? o : NEG_SLOPE * o;
    xb_out[n * D + d] = (ushort)bf16_rne(o);
    if (f32_out) f32_out[n * D + d] = o;
}

// ---------------- fallback (round-1 atomic path) ----------------
__global__ __launch_bounds__(256) void gine_edge_kernel(
    const float* __restrict__ x, const float* __restrict__ edge_attr,
    const float* __restrict__ We, const float* __restrict__ be,
    const int* __restrict__ src, const int* __restrict__ dst,
    float* __restrict__ agg)
{
    __shared__ float We_s[ED * D];
    __shared__ float be_s[D];
    int t = threadIdx.x;
    if (t < ED * D) We_s[t] = We[t];
    if (t < D) be_s[t] = be[t];
    __syncthreads();
    long gtid = (long)blockIdx.x * blockDim.x + t;
    int e = (int)(gtid >> 5), d = (int)(gtid & 31);
    if (e >= N_EDGES) return;
    int s = src[e], dn = dst[e];
    float acc = be_s[d];
#pragma unroll
    for (int k = 0; k < ED; ++k)
        acc += edge_attr[(long)e * ED + k] * We_s[k * D + d];
    float m = fmaxf(x[(long)s * D + d] + acc, 0.0f);
    atomicAdd(&agg[(long)dn * D + d], m);
}

__global__ __launch_bounds__(256) void gine_node_kernel(
    float* __restrict__ x, const float* __restrict__ agg,
    const float* __restrict__ W, const float* __restrict__ b)
{
    __shared__ float W_s[D * D];
    __shared__ float b_s[D];
    int t = threadIdx.x;
    for (int i = t; i < D * D; i += 256) W_s[i] = W[i];
    if (t < D) b_s[t] = b[t];
    __syncthreads();
    long gtid = (long)blockIdx.x * blockDim.x + t;
    int n = (int)(gtid >> 5), d = (int)(gtid & 31);
    if (n >= N_NODES) return;
    float h = x[(long)n * D + d] + agg[(long)n * D + d];
    float acc = b_s[d];
#pragma unroll
    for (int k = 0; k < D; ++k)
        acc += __shfl(h, k, D) * W_s[k * D + d];
    x[(long)n * D + d] = acc > 0.0f ? acc : NEG_SLOPE * acc;
}

// ---------------- launch ----------------

extern "C" void kernel_launch(void* const* d_in, const int* in_sizes, int n_in,
                              void* d_out, int out_size, void* d_ws, size_t ws_size,
                              hipStream_t stream) {
    const float* x_in      = (const float*)d_in[0];
    const float* edge_attr = (const float*)d_in[1];
    const float* W         = (const float*)d_in[2];
    const float* b         = (const float*)d_in[3];
    const float* We        = (const float*)d_in[4];
    const float* be        = (const float*)d_in[5];
    const int*   ei        = (const int*)d_in[6];
    const int* src = ei;
    const int* dst = ei + N_EDGES;

    const size_t xbytes  = (size_t)N_NODES * D * sizeof(float);
    const size_t xbbytes = (size_t)N_NODES * D * sizeof(ushort);  // 6.4 MB

    auto align = [](size_t v) { return (v + 255) & ~(size_t)255; };
    size_t off_xba  = 0;
    size_t off_xbb  = align(off_xba + xbbytes);
    size_t off_rp   = align(off_xbb + xbbytes);                     // row_ptr (N+1)
    size_t off_offs = align(off_rp + (N_NODES + 1) * sizeof(int));  // offs (N)
    size_t off_deg  = align(off_offs + N_NODES * sizeof(int));      // deg (N)
    size_t off_bs   = align(off_deg + N_NODES * sizeof(int));       // bsums (128)
    size_t off_rec  = align(off_bs + 128 * sizeof(int));            // rec (E * 32B)
    size_t need     = off_rec + (size_t)N_EDGES * 8 * sizeof(uint) + 256;

    if (ws_size >= need) {
        char* ws = (char*)d_ws;
        ushort* xbA    = (ushort*)(ws + off_xba);
        ushort* xbB    = (ushort*)(ws + off_xbb);
        int*   row_ptr = (int*)   (ws + off_rp);
        int*   offs    = (int*)   (ws + off_offs);
        int*   deg     = (int*)   (ws + off_deg);
        int*   bsums   = (int*)   (ws + off_bs);
        uint*  rec     = (uint*)  (ws + off_rec);

        pack_x_kernel<<<(N_NODES * D / 4 + 255) / 256, 256, 0, stream>>>(x_in, xbA);

        hipMemsetAsync(deg, 0, N_NODES * sizeof(int), stream);
        hist_kernel<<<(N_EDGES / 4 + 255) / 256, 256, 0, stream>>>(dst, deg);
        scan_phase1<<<NBLK, 1024, 0, stream>>>(deg, bsums);
        scan_phase2<<<1, 128, 0, stream>>>(bsums);
        scan_phase3<<<NBLK, 1024, 0, stream>>>(deg, bsums, row_ptr, offs);
        scatter_rec_kernel<<<(N_EDGES + 255) / 256, 256, 0, stream>>>(
            src, dst, edge_attr, offs, rec);

        float* xout = (float*)d_out;
        dim3 blk(256), grid((N_NODES + 7) / 8);
        gine_fused3_kernel<<<grid, blk, 0, stream>>>(xbA, xbB, nullptr, row_ptr, rec,
            W, b, We, be);
        gine_fused3_kernel<<<grid, blk, 0, stream>>>(xbB, xbA, nullptr, row_ptr, rec,
            W + D * D, b + D, We + ED * D, be + D);
        gine_fused3_kernel<<<grid, blk, 0, stream>>>(xbA, xbB, xout, row_ptr, rec,
            W + 2 * D * D, b + 2 * D, We + 2 * ED * D, be + 2 * D);
    } else {
        float* x = (float*)d_out;
        float* agg = (float*)d_ws;
        hipMemcpyAsync(x, x_in, xbytes, hipMemcpyDeviceToDevice, stream);
        dim3 eblk(256), egrid(((long)N_EDGES * D + 255) / 256);
        dim3 nblk(256), ngrid(((long)N_NODES * D + 255) / 256);
        for (int l = 0; l < 3; ++l) {
            hipMemsetAsync(agg, 0, xbytes, stream);
            gine_edge_kernel<<<egrid, eblk, 0, stream>>>(
                x, edge_attr, We + (size_t)l * ED * D, be + (size_t)l * D, src, dst, agg);
            gine_node_kernel<<<ngrid, nblk, 0, stream>>>(
                x, agg, W + (size_t)l * D * D, b + (size_t)l * D);
        }
    }
}